// Round 1
// baseline (134.726 us; speedup 1.0000x reference)
//
#include <hip/hip_runtime.h>

// RealtimeNgramProcessor: pack sliding windows base-512, sorted-table lookup.
// Inputs (int32 on device): x[256*8192], keys2[K2], vals2[K2], keys3[K3], vals3[K3]
// Output (int32): [2, 256, 8192] flat — plane 0 = bigram ids, plane 1 = trigram ids.

#define TOKEN_VOCAB 512

__device__ __forceinline__ int table_lookup(const int* __restrict__ keys,
                                            const int* __restrict__ vals,
                                            int K, int packed) {
    // lower_bound over sorted keys
    int lo = 0, hi = K;
    while (lo < hi) {
        int mid = (lo + hi) >> 1;
        if (keys[mid] < packed) lo = mid + 1; else hi = mid;
    }
    int pos = lo < (K - 1) ? lo : (K - 1);   // clip(searchsorted, 0, K-1)
    return (keys[pos] == packed) ? vals[pos] : 0;
}

__global__ void ngram_encode_kernel(const int* __restrict__ x,
                                    const int* __restrict__ keys2,
                                    const int* __restrict__ vals2, int K2,
                                    const int* __restrict__ keys3,
                                    const int* __restrict__ vals3, int K3,
                                    int* __restrict__ out, int total, int S) {
    int idx = blockIdx.x * blockDim.x + threadIdx.x;
    if (idx >= total) return;
    int s = idx & (S - 1);                   // S = 8192, power of two
    int t0 = x[idx];
    int t1 = (s >= 1) ? x[idx - 1] : 0;      // left pad with 0
    int t2 = (s >= 2) ? x[idx - 2] : 0;

    int k2 = t1 * TOKEN_VOCAB + t0;
    int k3 = (t2 * TOKEN_VOCAB + t1) * TOKEN_VOCAB + t0;

    out[idx]         = table_lookup(keys2, vals2, K2, k2);
    out[total + idx] = table_lookup(keys3, vals3, K3, k3);
}

extern "C" void kernel_launch(void* const* d_in, const int* in_sizes, int n_in,
                              void* d_out, int out_size, void* d_ws, size_t ws_size,
                              hipStream_t stream) {
    const int* x     = (const int*)d_in[0];
    const int* keys2 = (const int*)d_in[1];
    const int* vals2 = (const int*)d_in[2];
    const int* keys3 = (const int*)d_in[3];
    const int* vals3 = (const int*)d_in[4];
    int* out = (int*)d_out;

    const int total = in_sizes[0];           // B*S = 256*8192
    const int S = 8192;
    const int K2 = in_sizes[1];
    const int K3 = in_sizes[3];

    const int block = 256;
    const int grid = (total + block - 1) / block;
    ngram_encode_kernel<<<grid, block, 0, stream>>>(
        x, keys2, vals2, K2, keys3, vals3, K3, out, total, S);
}

// Round 2
// 100.663 us; speedup vs baseline: 1.3384x; 1.3384x over previous
//
#include <hip/hip_runtime.h>

// RealtimeNgramProcessor: pack sliding windows base-512, sorted-table lookup.
// R2 strategy: bigram -> 1 MB direct-map table in ws (1 load);
//              trigram -> 2^17-bucket start-index table in ws (chain of ~3 loads).
// Tables rebuilt every launch (ws re-poisoned by harness; same work per call).

#define TOKEN_VOCAB 512
#define SHIFT3 10
#define NBUCKET3 (1 << 17)          // key3 < 2^27, 2^17 buckets of 2^10
#define DIRECT2_ENTRIES (TOKEN_VOCAB * TOKEN_VOCAB)  // 262144

__global__ void build_direct2(const int* __restrict__ keys2,
                              const int* __restrict__ vals2, int K2,
                              int* __restrict__ direct2) {
    int i = blockIdx.x * blockDim.x + threadIdx.x;
    if (i < K2) direct2[keys2[i]] = vals2[i];
}

__global__ void build_start3(const int* __restrict__ keys3, int K3,
                             int* __restrict__ start3) {
    int b = blockIdx.x * blockDim.x + threadIdx.x;
    if (b > NBUCKET3) return;
    int target = b << SHIFT3;
    int lo = 0, hi = K3;
    while (lo < hi) {
        int mid = (lo + hi) >> 1;
        if (keys3[mid] < target) lo = mid + 1; else hi = mid;
    }
    start3[b] = lo;
}

__global__ void ngram_encode_fast(const int* __restrict__ x,
                                  const int* __restrict__ direct2,
                                  const int* __restrict__ start3,
                                  const int* __restrict__ keys3,
                                  const int* __restrict__ vals3,
                                  int* __restrict__ out, int total, int S) {
    int base = (blockIdx.x * blockDim.x + threadIdx.x) * 4;
    if (base >= total) return;
    int s = base & (S - 1);          // row offset; base%4==0 so s>=1 => s>=4
    const int4 cur = *(const int4*)(x + base);
    int tm1 = (s >= 1) ? x[base - 1] : 0;   // left pad 0 at row start
    int tm2 = (s >= 1) ? x[base - 2] : 0;
    int t[6] = {tm2, tm1, cur.x, cur.y, cur.z, cur.w};

    int o2[4], o3[4];
    int k3v[4], blo[4], bhi[4];
    #pragma unroll
    for (int j = 0; j < 4; ++j) {
        int k2 = t[j + 1] * TOKEN_VOCAB + t[j + 2];
        int k3 = (t[j] * TOKEN_VOCAB + t[j + 1]) * TOKEN_VOCAB + t[j + 2];
        k3v[j] = k3;
        o2[j] = direct2[k2];                    // independent loads, ILP
        int b = k3 >> SHIFT3;
        blo[j] = start3[b];
        bhi[j] = start3[b + 1];
    }
    #pragma unroll
    for (int j = 0; j < 4; ++j) {
        int v = 0;
        for (int p = blo[j]; p < bhi[j]; ++p) {
            int kv = keys3[p];
            if (kv >= k3v[j]) { v = (kv == k3v[j]) ? vals3[p] : 0; break; }
        }
        o3[j] = v;
    }
    *(int4*)(out + base)         = make_int4(o2[0], o2[1], o2[2], o2[3]);
    *(int4*)(out + total + base) = make_int4(o3[0], o3[1], o3[2], o3[3]);
}

// R1 fallback (ws too small): plain binary search per element.
__device__ __forceinline__ int table_lookup(const int* __restrict__ keys,
                                            const int* __restrict__ vals,
                                            int K, int packed) {
    int lo = 0, hi = K;
    while (lo < hi) {
        int mid = (lo + hi) >> 1;
        if (keys[mid] < packed) lo = mid + 1; else hi = mid;
    }
    int pos = lo < (K - 1) ? lo : (K - 1);
    return (keys[pos] == packed) ? vals[pos] : 0;
}

__global__ void ngram_encode_kernel(const int* __restrict__ x,
                                    const int* __restrict__ keys2,
                                    const int* __restrict__ vals2, int K2,
                                    const int* __restrict__ keys3,
                                    const int* __restrict__ vals3, int K3,
                                    int* __restrict__ out, int total, int S) {
    int idx = blockIdx.x * blockDim.x + threadIdx.x;
    if (idx >= total) return;
    int s = idx & (S - 1);
    int t0 = x[idx];
    int t1 = (s >= 1) ? x[idx - 1] : 0;
    int t2 = (s >= 2) ? x[idx - 2] : 0;
    int k2 = t1 * TOKEN_VOCAB + t0;
    int k3 = (t2 * TOKEN_VOCAB + t1) * TOKEN_VOCAB + t0;
    out[idx]         = table_lookup(keys2, vals2, K2, k2);
    out[total + idx] = table_lookup(keys3, vals3, K3, k3);
}

extern "C" void kernel_launch(void* const* d_in, const int* in_sizes, int n_in,
                              void* d_out, int out_size, void* d_ws, size_t ws_size,
                              hipStream_t stream) {
    const int* x     = (const int*)d_in[0];
    const int* keys2 = (const int*)d_in[1];
    const int* vals2 = (const int*)d_in[2];
    const int* keys3 = (const int*)d_in[3];
    const int* vals3 = (const int*)d_in[4];
    int* out = (int*)d_out;

    const int total = in_sizes[0];   // 256*8192
    const int S = 8192;
    const int K2 = in_sizes[1];
    const int K3 = in_sizes[3];

    const size_t ws_needed = (size_t)(DIRECT2_ENTRIES + NBUCKET3 + 1) * sizeof(int);
    if (ws_size >= ws_needed) {
        int* direct2 = (int*)d_ws;
        int* start3  = direct2 + DIRECT2_ENTRIES;

        hipMemsetAsync(direct2, 0, DIRECT2_ENTRIES * sizeof(int), stream);
        build_direct2<<<(K2 + 255) / 256, 256, 0, stream>>>(keys2, vals2, K2, direct2);
        build_start3<<<(NBUCKET3 + 1 + 255) / 256, 256, 0, stream>>>(keys3, K3, start3);

        const int block = 256;
        const int elems = total / 4;
        ngram_encode_fast<<<(elems + block - 1) / block, block, 0, stream>>>(
            x, direct2, start3, keys3, vals3, out, total, S);
    } else {
        const int block = 256;
        ngram_encode_kernel<<<(total + block - 1) / block, block, 0, stream>>>(
            x, keys2, vals2, K2, keys3, vals3, K3, out, total, S);
    }
}